// Round 17
// baseline (112.411 us; speedup 1.0000x reference)
//
#include <hip/hip_runtime.h>

typedef unsigned short u16;
typedef unsigned int u32;
typedef __bf16 bf16x8 __attribute__((ext_vector_type(8)));
typedef float f32x4 __attribute__((ext_vector_type(4)));
typedef u16 u16x4 __attribute__((ext_vector_type(4)));
typedef u16 u16x8 __attribute__((ext_vector_type(8)));

#define EPS 1e-5f

__device__ __forceinline__ u16 f2bf(float f) {
  unsigned u = __builtin_bit_cast(unsigned, f);
  u += 0x7FFFu + ((u >> 16) & 1u);   // RNE
  return (u16)(u >> 16);
}
__device__ __forceinline__ float bf2f(u16 h) {
  unsigned u = ((unsigned)h) << 16;
  return __builtin_bit_cast(float, u);
}

// ---------------- weight prep ----------------
__global__ void prep_weights(
    const float* __restrict__ wa, const float* __restrict__ g1, const float* __restrict__ b1,
    const float* __restrict__ m1, const float* __restrict__ v1,
    const float* __restrict__ w1, const float* __restrict__ g2, const float* __restrict__ b2,
    const float* __restrict__ m2, const float* __restrict__ v2,
    const float* __restrict__ w2,
    u16* __restrict__ Acat, u16* __restrict__ w1_o,
    float* __restrict__ bias1, float* __restrict__ bias2) {
  int c = blockIdx.x, k = threadIdx.x;
  float s1 = g1[c] / sqrtf(v1[c] + EPS);
  if (k < 256) Acat[c * 384 + k] = f2bf(wa[c * 256 + k] * s1);
  else         Acat[c * 384 + k] = f2bf(w2[c * 128 + (k - 256)]);
  if (c < 128) {
    float s2 = g2[c] / sqrtf(v2[c] + EPS);
    if (k < 256) w1_o[c * 256 + k] = f2bf(w1[c * 256 + k] * s2);
    if (k == 256) bias2[c] = b2[c] - m2[c] * s2;
  }
  if (k == 0) bias1[c] = b1[c] - m1[c] * s1;
}

// ---------------- FAT kernel: gconv (8/9 blocks) + gemm_h (1/9 blocks) ----------------
// Independent work overlapped in one launch: gconv is DS/VALU-bound, gemm_h is
// MFMA/HBM-bound; mixed residency hides each other's stalls. sbuf lives in d_out
// (overwritten by gemm_final afterwards) so it cannot alias xh.
__global__ __launch_bounds__(256, 2) void fat_kernel(
    const float* __restrict__ xl, const float* __restrict__ w1g,
    u16* __restrict__ sbuf,
    const u16* __restrict__ A, u16* __restrict__ xh,
    const float* __restrict__ bias) {
  __shared__ __attribute__((aligned(16))) char lds[40960];
  const int tid = threadIdx.x;
  const int bid = blockIdx.x;
  const int grp = bid / 9;
  const int slot = bid - grp * 9;

  if (slot == 4) {
    // ======== gemm_h: GELU(BN2(W1 @ x_local)) -> xh[b][p][256+c] ========
    u16 (*Al)[128][40] = (u16(*)[128][40])lds;
    u16 (*Bl)[128][40] = (u16(*)[128][40])(lds + 20480);
    const int b = grp >> 5;
    const int n0 = (grp & 31) * 128;
    const int wave = tid >> 6, lane = tid & 63;
    const int wr = wave >> 1, wc = wave & 1;
    const int lr = lane & 15, kg = lane >> 4;
    f32x4 acc[4][4] = {};
    const float* Bf = xl + (size_t)b * 256 * 4096;

    const int am = tid >> 1, apos = (tid & 1) * 16;
    const int nq = tid & 31, kq = tid >> 5;
    const int nb = n0 + nq * 4;

    u16x8 qa0, qa1;
    f32x4 qb[4];
    {
      qa0 = *(const u16x8*)(A + (size_t)am * 256 + 0 + apos);
      qa1 = *(const u16x8*)(A + (size_t)am * 256 + 0 + apos + 8);
#pragma unroll
      for (int i = 0; i < 4; ++i)
        qb[i] = *(const f32x4*)(Bf + (size_t)(kq * 4 + i) * 4096 + nb);
    }
    int cur = 0;
    for (int kt = 0; kt < 8; ++kt) {
      *(u16x8*)&Al[cur][am][apos] = qa0;
      *(u16x8*)&Al[cur][am][apos + 8] = qa1;
#pragma unroll
      for (int j = 0; j < 4; ++j) {
        u16x4 w = {f2bf(qb[0][j]), f2bf(qb[1][j]), f2bf(qb[2][j]), f2bf(qb[3][j])};
        *(u16x4*)&Bl[cur][nq * 4 + j][kq * 4] = w;
      }
      if (kt < 7) {
        int k1 = (kt + 1) * 32;
        qa0 = *(const u16x8*)(A + (size_t)am * 256 + k1 + apos);
        qa1 = *(const u16x8*)(A + (size_t)am * 256 + k1 + apos + 8);
#pragma unroll
        for (int i = 0; i < 4; ++i)
          qb[i] = *(const f32x4*)(Bf + (size_t)(k1 + kq * 4 + i) * 4096 + nb);
      }
      __syncthreads();
      bf16x8 af[4], bfr[4];
#pragma unroll
      for (int i = 0; i < 4; ++i) {
        af[i] = *(const bf16x8*)&Al[cur][wr * 64 + i * 16 + lr][kg * 8];
        bfr[i] = *(const bf16x8*)&Bl[cur][wc * 64 + i * 16 + lr][kg * 8];
      }
#pragma unroll
      for (int i = 0; i < 4; ++i)
#pragma unroll
        for (int j = 0; j < 4; ++j)
          acc[i][j] = __builtin_amdgcn_mfma_f32_16x16x32_bf16(af[i], bfr[j], acc[i][j], 0, 0, 0);
      cur ^= 1;
    }
    u16* O = xh + (size_t)b * 4096 * 384 + 256;  // concat offset
#pragma unroll
    for (int i = 0; i < 4; ++i) {
      int rb = wr * 64 + i * 16 + kg * 4;
      f32x4 b4 = *(const f32x4*)(bias + rb);
#pragma unroll
      for (int j = 0; j < 4; ++j) {
        int col = n0 + wc * 64 + j * 16 + lr;
        u16x4 w;
#pragma unroll
        for (int e = 0; e < 4; ++e) {
          float v = acc[i][j][e] + b4[e];
          v = 0.5f * v * (1.f + erff(v * 0.70710678118f));  // exact GELU
          w[e] = f2bf(v);
        }
        *(u16x4*)(O + (size_t)col * 384 + rb) = w;
      }
    }
  } else {
    // ======== gconv: grouped 3x3 conv + SiLU -> sbuf[b][q][p] ========
    float (*tile)[18][68] = (float(*)[18][68])lds;  // 4x18x68 f32 = 19.6KB
    const int idx = grp * 8 + (slot < 4 ? slot : slot - 1);
    const int band = idx & 3, q = (idx >> 2) & 63, b = idx >> 8;
    const float* xb = xl + ((size_t)b * 256 + 4 * q) * 4096;

    if (tid < 72) {
      int ci0 = tid / 18, r0_ = tid - ci0 * 18;
      float* rowp = &tile[ci0][r0_][0];
      rowp[0] = 0.f; rowp[65] = 0.f; rowp[66] = 0.f; rowp[67] = 0.f;
    }

    const int ci = tid >> 6, col = tid & 63;
    const int gy0 = band * 16 - 1;
    const float* cp = xb + (size_t)ci * 4096 + col;
    float v[18];
#pragma unroll
    for (int r = 0; r < 18; ++r) {
      int gy = gy0 + r;
      int gyc = min(max(gy, 0), 63);
      float raw = cp[gyc * 64];
      v[r] = ((unsigned)gy < 64u) ? raw : 0.f;
    }
#pragma unroll
    for (int r = 0; r < 18; ++r) tile[ci][r][col + 1] = v[r];

    float wq[36];
#pragma unroll
    for (int i = 0; i < 36; ++i) wq[i] = w1g[q * 36 + i];
    __syncthreads();

    const int qx = tid & 15, ry = tid >> 4;
    float a0 = 0.f, a1 = 0.f, a2 = 0.f, a3 = 0.f;
#pragma unroll
    for (int ci2 = 0; ci2 < 4; ++ci2) {
#pragma unroll
      for (int dy = 0; dy < 3; ++dy) {
        const float* rowp = &tile[ci2][ry + dy][qx * 4];
        f32x4 m = *(const f32x4*)rowp;
        float2 e = *(const float2*)(rowp + 4);
        float w0 = wq[ci2 * 9 + dy * 3 + 0];
        float w1_ = wq[ci2 * 9 + dy * 3 + 1];
        float w2_ = wq[ci2 * 9 + dy * 3 + 2];
        a0 += w0 * m[0] + w1_ * m[1] + w2_ * m[2];
        a1 += w0 * m[1] + w1_ * m[2] + w2_ * m[3];
        a2 += w0 * m[2] + w1_ * m[3] + w2_ * e.x;
        a3 += w0 * m[3] + w1_ * e.x  + w2_ * e.y;
      }
    }
    u16x4 o;
    o[0] = f2bf(a0 / (1.f + __expf(-a0)));
    o[1] = f2bf(a1 / (1.f + __expf(-a1)));
    o[2] = f2bf(a2 / (1.f + __expf(-a2)));
    o[3] = f2bf(a3 / (1.f + __expf(-a3)));
    u16* sp = sbuf + ((size_t)(b * 64 + q)) * 4096 + (band * 16 + ry) * 64 + qx * 4;
    *(u16x4*)sp = o;
  }
}

// ---------------- 1x1 conv over groups -> coords (float2) + wsum ----------------
__global__ __launch_bounds__(256) void coords_kernel(
    const u16* __restrict__ sbuf, const float* __restrict__ w2,
    const float* __restrict__ b2, float* __restrict__ coords,
    float* __restrict__ wsum) {
  __shared__ float sw2[128];
  const int tid = threadIdx.x;
  if (tid < 128) sw2[tid] = w2[tid];
  __syncthreads();
  const int b = blockIdx.y;
  const int p = blockIdx.x * 256 + tid;
  const u16* sp = sbuf + (size_t)b * 64 * 4096 + p;
  float ax = 0.f, ay = 0.f;
#pragma unroll 8
  for (int q = 0; q < 64; ++q) {
    float v = bf2f(sp[(size_t)q * 4096]);
    ax += sw2[q] * v;
    ay += sw2[64 + q] * v;
  }
  int y = p >> 6, x = p & 63;
  float ix = (64.f / 63.f) * (float)x + ax + b2[0] - 0.5f;
  float iy = (64.f / 63.f) * (float)y + ay + b2[1] - 0.5f;
  ((float2*)coords)[(size_t)b * 4096 + p] = make_float2(ix, iy);
  float x0f = floorf(ix), y0f = floorf(iy);
  int x0 = (int)x0f, y0 = (int)y0f;
  float wx1 = ix - x0f, wx0 = 1.f - wx1;
  float wy1 = iy - y0f, wy0 = 1.f - wy1;
  bool vx0 = (unsigned)x0 < 64u, vx1 = (unsigned)(x0 + 1) < 64u;
  bool vy0 = (unsigned)y0 < 64u, vy1 = (unsigned)(y0 + 1) < 64u;
  float s = (vx0 && vy0 ? wx0 * wy0 : 0.f) + (vx1 && vy0 ? wx1 * wy0 : 0.f) +
            (vx0 && vy1 ? wx0 * wy1 : 0.f) + (vx1 && vy1 ? wx1 * wy1 : 0.f);
  wsum[(size_t)b * 4096 + p] = s;
}

// ---------------- bilinear-sample x_guide -> xh[b][p][k] k<256 (pixel-major) ----------------
__global__ __launch_bounds__(256, 1) void sampler_kernel(
    const float* __restrict__ xg, const float* __restrict__ coords,
    u16* __restrict__ xh) {
  __shared__ u16 t[64 * 72];  // row stride 144B (16B-aligned)
  const int wg = blockIdx.x;
  const int id = (wg & 7) * 512 + (wg >> 3);  // XCD-chunked
  const int kq = id >> 10;                    // channel quad (64 ch)
  const int b = (id >> 6) & 15, row = id & 63;
  const int tid = threadIdx.x;
  const int px = tid & 63, ko = tid >> 6;     // ko wave-uniform
  const int p = row * 64 + px;
  float2 cd = ((const float2*)coords)[(size_t)b * 4096 + p];
  float ix = cd.x, iy = cd.y;
  float x0f = floorf(ix), y0f = floorf(iy);
  int x0 = (int)x0f, y0 = (int)y0f;
  float wx1 = ix - x0f, wx0 = 1.f - wx1;
  float wy1 = iy - y0f, wy0 = 1.f - wy1;
  bool vx0 = (unsigned)x0 < 64u, vx1 = (unsigned)(x0 + 1) < 64u;
  bool vy0 = (unsigned)y0 < 64u, vy1 = (unsigned)(y0 + 1) < 64u;
  int x0c = min(max(x0, 0), 63), x1c = min(max(x0 + 1, 0), 63);
  int y0c = min(max(y0, 0), 63), y1c = min(max(y0 + 1, 0), 63);
  float w00 = (vx0 && vy0) ? wx0 * wy0 : 0.f;
  float w10 = (vx1 && vy0) ? wx1 * wy0 : 0.f;
  float w01 = (vx0 && vy1) ? wx0 * wy1 : 0.f;
  float w11 = (vx1 && vy1) ? wx1 * wy1 : 0.f;
  const int i00 = y0c * 64 + x0c, i10 = y0c * 64 + x1c;
  const int i01 = y1c * 64 + x0c, i11 = y1c * 64 + x1c;
  const float* bb = xg + ((size_t)b * 256 + kq * 64 + ko * 16) * 4096;

  float v00[16], v10[16], v01[16], v11[16];
#pragma unroll
  for (int kk = 0; kk < 16; ++kk) {
    const float* bp = bb + (size_t)kk * 4096;
    v00[kk] = bp[i00];
    v10[kk] = bp[i10];
    v01[kk] = bp[i01];
    v11[kk] = bp[i11];
  }
  u16 o[16];
#pragma unroll
  for (int kk = 0; kk < 16; ++kk) {
    float v = w00 * v00[kk] + w10 * v10[kk] + w01 * v01[kk] + w11 * v11[kk];
    o[kk] = f2bf(v);
  }
  *(u16x8*)&t[px * 72 + ko * 16] = *(u16x8*)&o[0];
  *(u16x8*)&t[px * 72 + ko * 16 + 8] = *(u16x8*)&o[8];
  __syncthreads();
  const int seg = tid & 7, pxa = tid >> 3;
  u16* base = xh + ((size_t)b * 4096 + row * 64) * 384 + kq * 64 + seg * 8;
#pragma unroll
  for (int h = 0; h < 2; ++h) {
    int pp = pxa + h * 32;
    *(u16x8*)(base + (size_t)pp * 384) = *(const u16x8*)&t[pp * 72 + seg * 8];
  }
}

// ---------------- final GEMM: out = SiLU(Acat @ xh^T + bias1*wsum) ----------------
// Epilogue repacks through LDS (reusing Al) -> full-line coalesced f32x4 stores.
__global__ __launch_bounds__(256) void gemm_final(
    const u16* __restrict__ A,   // [256][384] bf16
    const u16* __restrict__ xh,  // [b][4096][384] pixel-major bf16
    const float* __restrict__ bias1, const float* __restrict__ wsum,
    float* __restrict__ out) {
  __shared__ __attribute__((aligned(16))) u16 Al[2][128][40];
  __shared__ u16 Bl[2][128][40];
  const int tid = threadIdx.x;
  const int wg = blockIdx.y * 64 + blockIdx.x;   // 0..1023
  const int nmb = (wg & 7) * 128 + (wg >> 3);    // XCD-chunked remap
  const int m = nmb & 1;
  const int n0 = ((nmb >> 1) & 31) * 128;
  const int b = nmb >> 6;
  const int wave = tid >> 6, lane = tid & 63;
  const int wr = wave >> 1, wc = wave & 1;
  const int lr = lane & 15, kg = lane >> 4;
  f32x4 acc[4][4] = {};
  const u16* Ab = A + (size_t)m * 128 * 384;
  const u16* Bb = xh + ((size_t)b * 4096 + n0) * 384;

  const int r0 = tid >> 2, pos0 = (tid & 3) * 8;
  const int r1 = (tid + 256) >> 2, pos1 = pos0;

  u16x8 pa0, pa1, pb0, pb1;
  {
    pa0 = *(const u16x8*)(Ab + (size_t)r0 * 384 + 0 + pos0);
    pb0 = *(const u16x8*)(Bb + (size_t)r0 * 384 + 0 + pos0);
    pa1 = *(const u16x8*)(Ab + (size_t)r1 * 384 + 0 + pos1);
    pb1 = *(const u16x8*)(Bb + (size_t)r1 * 384 + 0 + pos1);
  }
  int cur = 0;
  for (int kt = 0; kt < 12; ++kt) {
    *(u16x8*)&Al[cur][r0][pos0] = pa0;
    *(u16x8*)&Bl[cur][r0][pos0] = pb0;
    *(u16x8*)&Al[cur][r1][pos1] = pa1;
    *(u16x8*)&Bl[cur][r1][pos1] = pb1;
    if (kt < 11) {
      int k1 = (kt + 1) * 32;
      pa0 = *(const u16x8*)(Ab + (size_t)r0 * 384 + k1 + pos0);
      pb0 = *(const u16x8*)(Bb + (size_t)r0 * 384 + k1 + pos0);
      pa1 = *(const u16x8*)(Ab + (size_t)r1 * 384 + k1 + pos1);
      pb1 = *(const u16x8*)(Bb + (size_t)r1 * 384 + k1 + pos1);
    }
    __syncthreads();
    bf16x8 af[4], bfr[4];
#pragma unroll
    for (int i = 0; i < 4; ++i) {
      af[i] = *(const bf16x8*)&Al[cur][wr * 64 + i * 16 + lr][kg * 8];
      bfr[i] = *(const bf16x8*)&Bl[cur][wc * 64 + i * 16 + lr][kg * 8];
    }
#pragma unroll
    for (int i = 0; i < 4; ++i)
#pragma unroll
      for (int j = 0; j < 4; ++j)
        acc[i][j] = __builtin_amdgcn_mfma_f32_16x16x32_bf16(af[i], bfr[j], acc[i][j], 0, 0, 0);
    cur ^= 1;
  }

  // ---- epilogue: SiLU in regs -> LDS repack (reuse Al: 32x132 f32) ----
  float* rep = (float*)&Al[0][0][0];
  float* Ob = out + (size_t)b * 256 * 4096;
  float wsv[4];
#pragma unroll
  for (int j = 0; j < 4; ++j)
    wsv[j] = wsum[(size_t)b * 4096 + n0 + wc * 64 + j * 16 + lr];

#pragma unroll
  for (int i = 0; i < 4; ++i) {
    __syncthreads();  // rep region free (K-loop done / prev chunk stored)
    f32x4 b4 = *(const f32x4*)(bias1 + m * 128 + wr * 64 + i * 16 + kg * 4);
#pragma unroll
    for (int j = 0; j < 4; ++j) {
#pragma unroll
      for (int e = 0; e < 4; ++e) {
        float v = acc[i][j][e] + b4[e] * wsv[j];   // sampled bias (zeros padding)
        v = v / (1.f + __expf(-v));                // SiLU
        rep[(wr * 16 + kg * 4 + e) * 132 + wc * 64 + j * 16 + lr] = v;
      }
    }
    __syncthreads();
#pragma unroll
    for (int pass = 0; pass < 4; ++pass) {
      int lr_ = pass * 8 + (tid >> 5);   // 0..31 local row
      int lc_ = (tid & 31) * 4;          // 0..124 col (f32x4)
      f32x4 v4 = *(const f32x4*)&rep[lr_ * 132 + lc_];
      int grow = m * 128 + (lr_ >> 4) * 64 + i * 16 + (lr_ & 15);
      *(f32x4*)&Ob[(size_t)grow * 4096 + n0 + lc_] = v4;
    }
  }
}

// ---------------- launch ----------------
extern "C" void kernel_launch(void* const* d_in, const int* in_sizes, int n_in,
                              void* d_out, int out_size, void* d_ws, size_t ws_size,
                              hipStream_t stream) {
  const float* x_local = (const float*)d_in[0];
  const float* x_guide = (const float*)d_in[1];
  const float* w_align = (const float*)d_in[2];
  const float* bn1_g = (const float*)d_in[3];
  const float* bn1_b = (const float*)d_in[4];
  const float* bn1_m = (const float*)d_in[5];
  const float* bn1_v = (const float*)d_in[6];
  const float* w_off1 = (const float*)d_in[7];
  const float* w_off2 = (const float*)d_in[8];
  const float* b_off2 = (const float*)d_in[9];
  const float* w_mlp1 = (const float*)d_in[10];
  const float* bn2_g = (const float*)d_in[11];
  const float* bn2_b = (const float*)d_in[12];
  const float* bn2_m = (const float*)d_in[13];
  const float* bn2_v = (const float*)d_in[14];
  const float* w_mlp2 = (const float*)d_in[15];

  char* ws = (char*)d_ws;
  u16* Acat = (u16*)(ws + 0);               // 196608
  u16* w1_bf = (u16*)(ws + 196608);         // -> 262144
  float* bias1 = (float*)(ws + 262144);     // -> 263168
  float* bias2 = (float*)(ws + 263168);     // -> 263680
  float* wsum = (float*)(ws + 263680);      // -> 525824
  float* coords = (float*)(ws + 525824);    // -> 1050112
  u16* xh = (u16*)(ws + 1050112);           // 16*4096*384*2 = 50331648 -> 51381760
  // sbuf (8.4 MB bf16) now lives in d_out: gconv (fat) writes it, coords reads
  // it, gemm_final later overwrites all of d_out. No aliasing with xh, which
  // the fat kernel's gemm_h blocks write concurrently with gconv.
  u16* sbuf = (u16*)d_out;

  prep_weights<<<256, 384, 0, stream>>>(
      w_align, bn1_g, bn1_b, bn1_m, bn1_v,
      w_mlp1, bn2_g, bn2_b, bn2_m, bn2_v, w_mlp2,
      Acat, w1_bf, bias1, bias2);

  // gconv (4096 blocks) + gemm_h (512 blocks) overlapped: 4608 = 9*512
  fat_kernel<<<4608, 256, 0, stream>>>(
      x_local, w_off1, sbuf, w1_bf, xh, bias2);

  coords_kernel<<<dim3(16, 16), 256, 0, stream>>>(sbuf, w_off2, b_off2, coords, wsum);

  sampler_kernel<<<4096, 256, 0, stream>>>(x_guide, coords, xh);

  gemm_final<<<dim3(64, 16), 256, 0, stream>>>(Acat, xh, bias1, wsum, (float*)d_out);
}

// Round 18
// 107.333 us; speedup vs baseline: 1.0473x; 1.0473x over previous
//
#include <hip/hip_runtime.h>

typedef unsigned short u16;
typedef unsigned int u32;
typedef __bf16 bf16x8 __attribute__((ext_vector_type(8)));
typedef float f32x4 __attribute__((ext_vector_type(4)));
typedef u16 u16x4 __attribute__((ext_vector_type(4)));
typedef u16 u16x8 __attribute__((ext_vector_type(8)));

#define EPS 1e-5f

__device__ __forceinline__ u16 f2bf(float f) {
  unsigned u = __builtin_bit_cast(unsigned, f);
  u += 0x7FFFu + ((u >> 16) & 1u);   // RNE
  return (u16)(u >> 16);
}
__device__ __forceinline__ float bf2f(u16 h) {
  unsigned u = ((unsigned)h) << 16;
  return __builtin_bit_cast(float, u);
}

// ---------------- weight prep ----------------
__global__ void prep_weights(
    const float* __restrict__ wa, const float* __restrict__ g1, const float* __restrict__ b1,
    const float* __restrict__ m1, const float* __restrict__ v1,
    const float* __restrict__ w1, const float* __restrict__ g2, const float* __restrict__ b2,
    const float* __restrict__ m2, const float* __restrict__ v2,
    const float* __restrict__ w2,
    u16* __restrict__ Acat, u16* __restrict__ w1_o,
    float* __restrict__ bias1, float* __restrict__ bias2) {
  int c = blockIdx.x, k = threadIdx.x;
  float s1 = g1[c] / sqrtf(v1[c] + EPS);
  if (k < 256) Acat[c * 384 + k] = f2bf(wa[c * 256 + k] * s1);
  else         Acat[c * 384 + k] = f2bf(w2[c * 128 + (k - 256)]);
  if (c < 128) {
    float s2 = g2[c] / sqrtf(v2[c] + EPS);
    if (k < 256) w1_o[c * 256 + k] = f2bf(w1[c * 256 + k] * s2);
    if (k == 256) bias2[c] = b2[c] - m2[c] * s2;
  }
  if (k == 0) bias1[c] = b1[c] - m1[c] * s1;
}

// ---------------- grouped 3x3 conv + SiLU -> s[b][q][p] (bf16) ----------------
__global__ __launch_bounds__(256) void gconv_kernel(
    const float* __restrict__ xl, const float* __restrict__ w1,
    u16* __restrict__ sbuf) {
  __shared__ float tile[4][18][68];  // row stride 272B (16B-aligned)
  const int tid = threadIdx.x;
  const int band = blockIdx.x;
  const int q = blockIdx.y;
  const int b = blockIdx.z;
  const float* xb = xl + ((size_t)b * 256 + 4 * q) * 4096;

  if (tid < 72) {
    int ci0 = tid / 18, r0_ = tid - ci0 * 18;
    float* rowp = &tile[ci0][r0_][0];
    rowp[0] = 0.f; rowp[65] = 0.f; rowp[66] = 0.f; rowp[67] = 0.f;
  }

  const int ci = tid >> 6, col = tid & 63;
  const int gy0 = band * 16 - 1;
  const float* cp = xb + (size_t)ci * 4096 + col;
  float v[18];
#pragma unroll
  for (int r = 0; r < 18; ++r) {
    int gy = gy0 + r;
    int gyc = min(max(gy, 0), 63);
    float raw = cp[gyc * 64];
    v[r] = ((unsigned)gy < 64u) ? raw : 0.f;
  }
#pragma unroll
  for (int r = 0; r < 18; ++r) tile[ci][r][col + 1] = v[r];

  float wq[36];
#pragma unroll
  for (int i = 0; i < 36; ++i) wq[i] = w1[q * 36 + i];
  __syncthreads();

  const int qx = tid & 15, ry = tid >> 4;
  float a0 = 0.f, a1 = 0.f, a2 = 0.f, a3 = 0.f;
#pragma unroll
  for (int ci2 = 0; ci2 < 4; ++ci2) {
#pragma unroll
    for (int dy = 0; dy < 3; ++dy) {
      const float* rowp = &tile[ci2][ry + dy][qx * 4];
      f32x4 m = *(const f32x4*)rowp;
      float2 e = *(const float2*)(rowp + 4);
      float w0 = wq[ci2 * 9 + dy * 3 + 0];
      float w1_ = wq[ci2 * 9 + dy * 3 + 1];
      float w2_ = wq[ci2 * 9 + dy * 3 + 2];
      a0 += w0 * m[0] + w1_ * m[1] + w2_ * m[2];
      a1 += w0 * m[1] + w1_ * m[2] + w2_ * m[3];
      a2 += w0 * m[2] + w1_ * m[3] + w2_ * e.x;
      a3 += w0 * m[3] + w1_ * e.x  + w2_ * e.y;
    }
  }
  u16x4 o;
  o[0] = f2bf(a0 / (1.f + __expf(-a0)));
  o[1] = f2bf(a1 / (1.f + __expf(-a1)));
  o[2] = f2bf(a2 / (1.f + __expf(-a2)));
  o[3] = f2bf(a3 / (1.f + __expf(-a3)));
  u16* sp = sbuf + ((size_t)(b * 64 + q)) * 4096 + (band * 16 + ry) * 64 + qx * 4;
  *(u16x4*)sp = o;
}

// ---------------- 1x1 conv over groups -> coords (float2) + wsum ----------------
__global__ __launch_bounds__(256) void coords_kernel(
    const u16* __restrict__ sbuf, const float* __restrict__ w2,
    const float* __restrict__ b2, float* __restrict__ coords,
    float* __restrict__ wsum) {
  __shared__ float sw2[128];
  const int tid = threadIdx.x;
  if (tid < 128) sw2[tid] = w2[tid];
  __syncthreads();
  const int b = blockIdx.y;
  const int p = blockIdx.x * 256 + tid;
  const u16* sp = sbuf + (size_t)b * 64 * 4096 + p;
  float ax = 0.f, ay = 0.f;
#pragma unroll 8
  for (int q = 0; q < 64; ++q) {
    float v = bf2f(sp[(size_t)q * 4096]);
    ax += sw2[q] * v;
    ay += sw2[64 + q] * v;
  }
  int y = p >> 6, x = p & 63;
  float ix = (64.f / 63.f) * (float)x + ax + b2[0] - 0.5f;
  float iy = (64.f / 63.f) * (float)y + ay + b2[1] - 0.5f;
  ((float2*)coords)[(size_t)b * 4096 + p] = make_float2(ix, iy);
  float x0f = floorf(ix), y0f = floorf(iy);
  int x0 = (int)x0f, y0 = (int)y0f;
  float wx1 = ix - x0f, wx0 = 1.f - wx1;
  float wy1 = iy - y0f, wy0 = 1.f - wy1;
  bool vx0 = (unsigned)x0 < 64u, vx1 = (unsigned)(x0 + 1) < 64u;
  bool vy0 = (unsigned)y0 < 64u, vy1 = (unsigned)(y0 + 1) < 64u;
  float s = (vx0 && vy0 ? wx0 * wy0 : 0.f) + (vx1 && vy0 ? wx1 * wy0 : 0.f) +
            (vx0 && vy1 ? wx0 * wy1 : 0.f) + (vx1 && vy1 ? wx1 * wy1 : 0.f);
  wsum[(size_t)b * 4096 + p] = s;
}

// ---------------- bilinear-sample x_guide -> xh[b][p][k] k<256 (pixel-major) ----------------
// Horizontal tap pairing: one float2 load per row fetches BOTH x-neighbors
// (xb2 = clamp(x0,0,62); clamp cases resolved by select). 32 gathers/thread
// instead of 64 -- tests the instruction-issue-bound theory.
__global__ __launch_bounds__(256, 1) void sampler_kernel(
    const float* __restrict__ xg, const float* __restrict__ coords,
    u16* __restrict__ xh) {
  __shared__ u16 t[64 * 72];  // row stride 144B (16B-aligned)
  const int wg = blockIdx.x;
  const int id = (wg & 7) * 512 + (wg >> 3);  // XCD-chunked
  const int kq = id >> 10;                    // channel quad (64 ch)
  const int b = (id >> 6) & 15, row = id & 63;
  const int tid = threadIdx.x;
  const int px = tid & 63, ko = tid >> 6;     // ko wave-uniform
  const int p = row * 64 + px;
  float2 cd = ((const float2*)coords)[(size_t)b * 4096 + p];
  float ix = cd.x, iy = cd.y;
  float x0f = floorf(ix), y0f = floorf(iy);
  int x0 = (int)x0f, y0 = (int)y0f;
  float wx1 = ix - x0f, wx0 = 1.f - wx1;
  float wy1 = iy - y0f, wy0 = 1.f - wy1;
  bool vx0 = (unsigned)x0 < 64u, vx1 = (unsigned)(x0 + 1) < 64u;
  bool vy0 = (unsigned)y0 < 64u, vy1 = (unsigned)(y0 + 1) < 64u;
  int x0c = min(max(x0, 0), 63), x1c = min(max(x0 + 1, 0), 63);
  int y0c = min(max(y0, 0), 63), y1c = min(max(y0 + 1, 0), 63);
  float w00 = (vx0 && vy0) ? wx0 * wy0 : 0.f;
  float w10 = (vx1 && vy0) ? wx1 * wy0 : 0.f;
  float w01 = (vx0 && vy1) ? wx0 * wy1 : 0.f;
  float w11 = (vx1 && vy1) ? wx1 * wy1 : 0.f;
  // paired-x window base (always in-bounds: xb2 in [0,62])
  const int xb2 = min(max(x0, 0), 62);
  const bool sel0 = (x0c != xb2);   // v00 = sel0 ? f.y : f.x
  const bool sel1 = (x1c != xb2);   // v10 = sel1 ? f.y : f.x
  const int i0t = y0c * 64 + xb2;   // top row pair
  const int i0b = y1c * 64 + xb2;   // bottom row pair
  const float* bb = xg + ((size_t)b * 256 + kq * 64 + ko * 16) * 4096;

  // phase A: 32 float2 gathers (both x-taps per load), all in flight
  float2 ft[16], fb_[16];
#pragma unroll
  for (int kk = 0; kk < 16; ++kk) {
    const float* bp = bb + (size_t)kk * 4096;
    ft[kk] = *(const float2*)(bp + i0t);
    fb_[kk] = *(const float2*)(bp + i0b);
  }
  // phase B: select + combine + pack
  u16 o[16];
#pragma unroll
  for (int kk = 0; kk < 16; ++kk) {
    float v00 = sel0 ? ft[kk].y : ft[kk].x;
    float v10 = sel1 ? ft[kk].y : ft[kk].x;
    float v01 = sel0 ? fb_[kk].y : fb_[kk].x;
    float v11 = sel1 ? fb_[kk].y : fb_[kk].x;
    float v = w00 * v00 + w10 * v10 + w01 * v01 + w11 * v11;
    o[kk] = f2bf(v);
  }
  *(u16x8*)&t[px * 72 + ko * 16] = *(u16x8*)&o[0];
  *(u16x8*)&t[px * 72 + ko * 16 + 8] = *(u16x8*)&o[8];
  __syncthreads();
  const int seg = tid & 7, pxa = tid >> 3;
  u16* base = xh + ((size_t)b * 4096 + row * 64) * 384 + kq * 64 + seg * 8;
#pragma unroll
  for (int h = 0; h < 2; ++h) {
    int pp = pxa + h * 32;
    *(u16x8*)(base + (size_t)pp * 384) = *(const u16x8*)&t[pp * 72 + seg * 8];
  }
}

// ---------------- h GEMM: GELU(BN2(W1 @ x_local)) -> xh[b][p][256+c] ----------------
__global__ __launch_bounds__(256, 2) void gemm_h(
    const u16* __restrict__ A, const float* __restrict__ Bsrc,
    u16* __restrict__ xh, const float* __restrict__ bias) {
  __shared__ u16 Al[2][128][40];
  __shared__ u16 Bl[2][128][40];
  const int tid = threadIdx.x;
  const int b = blockIdx.y;
  const int n0 = blockIdx.x * 128;
  const int wave = tid >> 6, lane = tid & 63;
  const int wr = wave >> 1, wc = wave & 1;
  const int lr = lane & 15, kg = lane >> 4;
  f32x4 acc[4][4] = {};
  const float* Bf = Bsrc + (size_t)b * 256 * 4096;

  const int am = tid >> 1, apos = (tid & 1) * 16;
  const int nq = tid & 31, kq = tid >> 5;
  const int nb = n0 + nq * 4;

  u16x8 qa0, qa1;
  f32x4 qb[4];
  {
    qa0 = *(const u16x8*)(A + (size_t)am * 256 + 0 + apos);
    qa1 = *(const u16x8*)(A + (size_t)am * 256 + 0 + apos + 8);
#pragma unroll
    for (int i = 0; i < 4; ++i)
      qb[i] = *(const f32x4*)(Bf + (size_t)(kq * 4 + i) * 4096 + nb);
  }
  int cur = 0;
  for (int kt = 0; kt < 8; ++kt) {
    *(u16x8*)&Al[cur][am][apos] = qa0;
    *(u16x8*)&Al[cur][am][apos + 8] = qa1;
#pragma unroll
    for (int j = 0; j < 4; ++j) {
      u16x4 w = {f2bf(qb[0][j]), f2bf(qb[1][j]), f2bf(qb[2][j]), f2bf(qb[3][j])};
      *(u16x4*)&Bl[cur][nq * 4 + j][kq * 4] = w;
    }
    if (kt < 7) {
      int k1 = (kt + 1) * 32;
      qa0 = *(const u16x8*)(A + (size_t)am * 256 + k1 + apos);
      qa1 = *(const u16x8*)(A + (size_t)am * 256 + k1 + apos + 8);
#pragma unroll
      for (int i = 0; i < 4; ++i)
        qb[i] = *(const f32x4*)(Bf + (size_t)(k1 + kq * 4 + i) * 4096 + nb);
    }
    __syncthreads();
    bf16x8 af[4], bfr[4];
#pragma unroll
    for (int i = 0; i < 4; ++i) {
      af[i] = *(const bf16x8*)&Al[cur][wr * 64 + i * 16 + lr][kg * 8];
      bfr[i] = *(const bf16x8*)&Bl[cur][wc * 64 + i * 16 + lr][kg * 8];
    }
#pragma unroll
    for (int i = 0; i < 4; ++i)
#pragma unroll
      for (int j = 0; j < 4; ++j)
        acc[i][j] = __builtin_amdgcn_mfma_f32_16x16x32_bf16(af[i], bfr[j], acc[i][j], 0, 0, 0);
    cur ^= 1;
  }
  u16* O = xh + (size_t)b * 4096 * 384 + 256;  // concat offset
#pragma unroll
  for (int i = 0; i < 4; ++i) {
    int rb = wr * 64 + i * 16 + kg * 4;
    f32x4 b4 = *(const f32x4*)(bias + rb);
#pragma unroll
    for (int j = 0; j < 4; ++j) {
      int col = n0 + wc * 64 + j * 16 + lr;
      u16x4 w;
#pragma unroll
      for (int e = 0; e < 4; ++e) {
        float v = acc[i][j][e] + b4[e];
        v = 0.5f * v * (1.f + erff(v * 0.70710678118f));  // exact GELU
        w[e] = f2bf(v);
      }
      *(u16x4*)(O + (size_t)col * 384 + rb) = w;
    }
  }
}

// ---------------- final GEMM: out = SiLU(Acat @ xh^T + bias1*wsum) ----------------
__global__ __launch_bounds__(256) void gemm_final(
    const u16* __restrict__ A,   // [256][384] bf16
    const u16* __restrict__ xh,  // [b][4096][384] pixel-major bf16
    const float* __restrict__ bias1, const float* __restrict__ wsum,
    float* __restrict__ out) {
  __shared__ __attribute__((aligned(16))) u16 Al[2][128][40];
  __shared__ u16 Bl[2][128][40];
  const int tid = threadIdx.x;
  const int wg = blockIdx.y * 64 + blockIdx.x;   // 0..1023
  const int nmb = (wg & 7) * 128 + (wg >> 3);    // XCD-chunked remap
  const int m = nmb & 1;
  const int n0 = ((nmb >> 1) & 31) * 128;
  const int b = nmb >> 6;
  const int wave = tid >> 6, lane = tid & 63;
  const int wr = wave >> 1, wc = wave & 1;
  const int lr = lane & 15, kg = lane >> 4;
  f32x4 acc[4][4] = {};
  const u16* Ab = A + (size_t)m * 128 * 384;
  const u16* Bb = xh + ((size_t)b * 4096 + n0) * 384;

  const int r0 = tid >> 2, pos0 = (tid & 3) * 8;
  const int r1 = (tid + 256) >> 2, pos1 = pos0;

  u16x8 pa0, pa1, pb0, pb1;
  {
    pa0 = *(const u16x8*)(Ab + (size_t)r0 * 384 + 0 + pos0);
    pb0 = *(const u16x8*)(Bb + (size_t)r0 * 384 + 0 + pos0);
    pa1 = *(const u16x8*)(Ab + (size_t)r1 * 384 + 0 + pos1);
    pb1 = *(const u16x8*)(Bb + (size_t)r1 * 384 + 0 + pos1);
  }
  int cur = 0;
  for (int kt = 0; kt < 12; ++kt) {
    *(u16x8*)&Al[cur][r0][pos0] = pa0;
    *(u16x8*)&Bl[cur][r0][pos0] = pb0;
    *(u16x8*)&Al[cur][r1][pos1] = pa1;
    *(u16x8*)&Bl[cur][r1][pos1] = pb1;
    if (kt < 11) {
      int k1 = (kt + 1) * 32;
      pa0 = *(const u16x8*)(Ab + (size_t)r0 * 384 + k1 + pos0);
      pb0 = *(const u16x8*)(Bb + (size_t)r0 * 384 + k1 + pos0);
      pa1 = *(const u16x8*)(Ab + (size_t)r1 * 384 + k1 + pos1);
      pb1 = *(const u16x8*)(Bb + (size_t)r1 * 384 + k1 + pos1);
    }
    __syncthreads();
    bf16x8 af[4], bfr[4];
#pragma unroll
    for (int i = 0; i < 4; ++i) {
      af[i] = *(const bf16x8*)&Al[cur][wr * 64 + i * 16 + lr][kg * 8];
      bfr[i] = *(const bf16x8*)&Bl[cur][wc * 64 + i * 16 + lr][kg * 8];
    }
#pragma unroll
    for (int i = 0; i < 4; ++i)
#pragma unroll
      for (int j = 0; j < 4; ++j)
        acc[i][j] = __builtin_amdgcn_mfma_f32_16x16x32_bf16(af[i], bfr[j], acc[i][j], 0, 0, 0);
    cur ^= 1;
  }

  // ---- epilogue: SiLU in regs -> LDS repack (reuse Al: 32x132 f32) ----
  float* rep = (float*)&Al[0][0][0];
  float* Ob = out + (size_t)b * 256 * 4096;
  float wsv[4];
#pragma unroll
  for (int j = 0; j < 4; ++j)
    wsv[j] = wsum[(size_t)b * 4096 + n0 + wc * 64 + j * 16 + lr];

#pragma unroll
  for (int i = 0; i < 4; ++i) {
    __syncthreads();  // rep region free (K-loop done / prev chunk stored)
    f32x4 b4 = *(const f32x4*)(bias1 + m * 128 + wr * 64 + i * 16 + kg * 4);
#pragma unroll
    for (int j = 0; j < 4; ++j) {
#pragma unroll
      for (int e = 0; e < 4; ++e) {
        float v = acc[i][j][e] + b4[e] * wsv[j];   // sampled bias (zeros padding)
        v = v / (1.f + __expf(-v));                // SiLU
        rep[(wr * 16 + kg * 4 + e) * 132 + wc * 64 + j * 16 + lr] = v;
      }
    }
    __syncthreads();
#pragma unroll
    for (int pass = 0; pass < 4; ++pass) {
      int lr_ = pass * 8 + (tid >> 5);   // 0..31 local row
      int lc_ = (tid & 31) * 4;          // 0..124 col (f32x4)
      f32x4 v4 = *(const f32x4*)&rep[lr_ * 132 + lc_];
      int grow = m * 128 + (lr_ >> 4) * 64 + i * 16 + (lr_ & 15);
      *(f32x4*)&Ob[(size_t)grow * 4096 + n0 + lc_] = v4;
    }
  }
}

// ---------------- launch ----------------
extern "C" void kernel_launch(void* const* d_in, const int* in_sizes, int n_in,
                              void* d_out, int out_size, void* d_ws, size_t ws_size,
                              hipStream_t stream) {
  const float* x_local = (const float*)d_in[0];
  const float* x_guide = (const float*)d_in[1];
  const float* w_align = (const float*)d_in[2];
  const float* bn1_g = (const float*)d_in[3];
  const float* bn1_b = (const float*)d_in[4];
  const float* bn1_m = (const float*)d_in[5];
  const float* bn1_v = (const float*)d_in[6];
  const float* w_off1 = (const float*)d_in[7];
  const float* w_off2 = (const float*)d_in[8];
  const float* b_off2 = (const float*)d_in[9];
  const float* w_mlp1 = (const float*)d_in[10];
  const float* bn2_g = (const float*)d_in[11];
  const float* bn2_b = (const float*)d_in[12];
  const float* bn2_m = (const float*)d_in[13];
  const float* bn2_v = (const float*)d_in[14];
  const float* w_mlp2 = (const float*)d_in[15];

  char* ws = (char*)d_ws;
  u16* Acat = (u16*)(ws + 0);               // 196608
  u16* w1_bf = (u16*)(ws + 196608);         // -> 262144
  float* bias1 = (float*)(ws + 262144);     // -> 263168
  float* bias2 = (float*)(ws + 263168);     // -> 263680
  float* wsum = (float*)(ws + 263680);      // -> 525824
  float* coords = (float*)(ws + 525824);    // -> 1050112
  u16* xh = (u16*)(ws + 1050112);           // 16*4096*384*2 = 50331648 -> 51381760
  // sbuf (8.4 MB bf16) lives in d_out: gconv writes it, coords reads it,
  // gemm_final overwrites all of d_out at the end (serial stream order).
  u16* sbuf = (u16*)d_out;

  prep_weights<<<256, 384, 0, stream>>>(
      w_align, bn1_g, bn1_b, bn1_m, bn1_v,
      w_mlp1, bn2_g, bn2_b, bn2_m, bn2_v, w_mlp2,
      Acat, w1_bf, bias1, bias2);

  gconv_kernel<<<dim3(4, 64, 16), 256, 0, stream>>>(x_local, w_off1, sbuf);

  coords_kernel<<<dim3(16, 16), 256, 0, stream>>>(sbuf, w_off2, b_off2, coords, wsum);

  sampler_kernel<<<4096, 256, 0, stream>>>(x_guide, coords, xh);

  gemm_h<<<dim3(32, 16), 256, 0, stream>>>(w1_bf, x_local, xh, bias2);

  gemm_final<<<dim3(64, 16), 256, 0, stream>>>(Acat, xh, bias1, wsum, (float*)d_out);
}